// Round 3
// baseline (150.580 us; speedup 1.0000x reference)
//
#include <hip/hip_runtime.h>

#define LN_EPS 1e-5f

constexpr int Bn = 4, Nn = 256, Dn = 256, Hn = 256;

// ws layout (floats):
//   aA  @ 0        (1024*256)
//   bB  @ 262144   (1024*256)
//   rC  @ 524288   (1024 r + 4 C) -- atomic accumulators, zeroed in gemm
//   rel @ 525568   (1024)

// ---------------------------------------------------------------------------
// Kernel 1: aA[m,h] = x[m,:]@Wg[:D,h] + bg[h]  (half=0)
//           bB[m,h] = x[m,:]@Wg[D:,h]          (half=1)
// Block: 4-row m-tile, 512 threads = (h4 in [0,64), dc in [0,8)).
// Thread loads W as float4 along h (1KB/wave coalesced), d-chunk of 32.
// 8-way d-chunk partials combined in LDS. Block (0,0) zeroes rC.
// ---------------------------------------------------------------------------
__global__ __launch_bounds__(512) void gemm_ab_kernel(
    const float* __restrict__ x, const float* __restrict__ Wg,
    const float* __restrict__ bg, float* __restrict__ aA,
    float* __restrict__ bB, float* __restrict__ rC)
{
    int mt = blockIdx.x;     // 0..255
    int half = blockIdx.y;   // 0 -> a, 1 -> b
    int m0 = mt * 4;
    int t = threadIdx.x;

    if (mt == 0 && half == 0) {
        for (int k = t; k < 1028; k += 512) rC[k] = 0.0f;
    }

    __shared__ float xs[4][256];
    __shared__ float accP[8][4][256];

    if (t < 256)
        reinterpret_cast<float4*>(&xs[0][0])[t] =
            reinterpret_cast<const float4*>(x + m0 * Dn)[t];
    __syncthreads();

    int h4 = t & 63;         // 4-wide h group
    int dc = t >> 6;         // 0..7, wave-uniform
    const float* Wp = Wg + (half ? Dn * Hn : 0) + h4 * 4;

    float4 acc[4];
#pragma unroll
    for (int m = 0; m < 4; ++m) acc[m] = make_float4(0.f, 0.f, 0.f, 0.f);

#pragma unroll 4
    for (int dd = 0; dd < 32; ++dd) {
        int d = dc * 32 + dd;
        float4 w = *reinterpret_cast<const float4*>(Wp + d * Hn);
#pragma unroll
        for (int m = 0; m < 4; ++m) {
            float xv = xs[m][d];
            acc[m].x = fmaf(xv, w.x, acc[m].x);
            acc[m].y = fmaf(xv, w.y, acc[m].y);
            acc[m].z = fmaf(xv, w.z, acc[m].z);
            acc[m].w = fmaf(xv, w.w, acc[m].w);
        }
    }
#pragma unroll
    for (int m = 0; m < 4; ++m)
        *reinterpret_cast<float4*>(&accP[dc][m][h4 * 4]) = acc[m];
    __syncthreads();

    // combine: 512 threads = (h = t&255, mh = t>>8), m in {2mh, 2mh+1}
    int h = t & 255;
    int mh = t >> 8;
    float binit = half ? 0.0f : bg[h];
    float* outp = half ? bB : aA;
#pragma unroll
    for (int mi = 0; mi < 2; ++mi) {
        int m = mh * 2 + mi;
        float v = binit;
#pragma unroll
        for (int c = 0; c < 8; ++c) v += accP[c][m][h];
        outp[(m0 + m) * Hn + h] = v;
    }
}

// ---------------------------------------------------------------------------
// Kernel 2: fused pair block. Block = (b, 2-row i-tile), 512 threads, grid 512.
// Phase 1 (thread = (j, h-half)): LN stats for both i-rows, float4 bB row reads.
// Phase 2 (thread = (h4, j-chunk)): float4 bB reads coalesced (1KB/wave/row),
//   wave-uniform invL broadcast, acc += inv*relu(A+b); LDS-combine, atomics.
// ---------------------------------------------------------------------------
__global__ __launch_bounds__(512) void pair_kernel(
    const float* __restrict__ aA, const float* __restrict__ bB,
    float* __restrict__ rC)
{
    int b  = blockIdx.x >> 7;
    int i0 = (blockIdx.x & 127) * 2;
    int t = threadIdx.x;

    __shared__ float A[2][256];
    __shared__ float invL[2][256];
    __shared__ float sP[2][2][256];   // [i][half][j]
    __shared__ float qP[2][2][256];
    __shared__ float red[2][8][256];  // [i][chunk][h]

    if (t < 128)
        reinterpret_cast<float4*>(&A[0][0])[t] =
            reinterpret_cast<const float4*>(aA + (b * Nn + i0) * Hn)[t];
    __syncthreads();

    // ---- phase 1: stats ----
    {
        int j = t & 255;
        int c2 = t >> 8;               // h-half, wave-uniform
        const float* brow = bB + (b * Nn + j) * Hn;
        float s0 = 0.f, q0 = 0.f, s1 = 0.f, q1 = 0.f;
        int hbase = c2 * 128;
#pragma unroll 4
        for (int hh = 0; hh < 128; hh += 4) {
            int h = hbase + hh;
            float4 b4 = *reinterpret_cast<const float4*>(brow + h);
            float4 a0 = *reinterpret_cast<const float4*>(&A[0][h]);
            float4 a1 = *reinterpret_cast<const float4*>(&A[1][h]);
            float v;
            v = fmaxf(a0.x + b4.x, 0.f); s0 += v; q0 = fmaf(v, v, q0);
            v = fmaxf(a0.y + b4.y, 0.f); s0 += v; q0 = fmaf(v, v, q0);
            v = fmaxf(a0.z + b4.z, 0.f); s0 += v; q0 = fmaf(v, v, q0);
            v = fmaxf(a0.w + b4.w, 0.f); s0 += v; q0 = fmaf(v, v, q0);
            v = fmaxf(a1.x + b4.x, 0.f); s1 += v; q1 = fmaf(v, v, q1);
            v = fmaxf(a1.y + b4.y, 0.f); s1 += v; q1 = fmaf(v, v, q1);
            v = fmaxf(a1.z + b4.z, 0.f); s1 += v; q1 = fmaf(v, v, q1);
            v = fmaxf(a1.w + b4.w, 0.f); s1 += v; q1 = fmaf(v, v, q1);
        }
        sP[0][c2][j] = s0; qP[0][c2][j] = q0;
        sP[1][c2][j] = s1; qP[1][c2][j] = q1;
    }
    __syncthreads();
    {
        // 512 threads = (j = t&255, i = t>>8)
        int j = t & 255;
        int i = t >> 8;                // wave-uniform
        float S = sP[i][0][j] + sP[i][1][j];
        float Q = qP[i][0][j] + qP[i][1][j];
        float m = S * (1.f / 256.f);
        float inv = rsqrtf(Q * (1.f / 256.f) - m * m + LN_EPS);
        invL[i][j] = inv;
        float y = -m * inv;
#pragma unroll
        for (int off = 32; off >= 1; off >>= 1) y += __shfl_xor(y, off, 64);
        if ((t & 63) == 0) atomicAdd(&rC[1024 + b], y);
    }
    __syncthreads();

    // ---- phase 2: weighted accumulation ----
    {
        int h4 = t & 63;
        int c = t >> 6;                // j-chunk, wave-uniform
        float4 a0 = *reinterpret_cast<const float4*>(&A[0][h4 * 4]);
        float4 a1 = *reinterpret_cast<const float4*>(&A[1][h4 * 4]);
        const float* bbase = bB + b * Nn * Hn + h4 * 4;
        float4 acc0 = make_float4(0.f, 0.f, 0.f, 0.f);
        float4 acc1 = make_float4(0.f, 0.f, 0.f, 0.f);
#pragma unroll 8
        for (int jj = 0; jj < 32; ++jj) {
            int j = c * 32 + jj;
            float4 b4 = *reinterpret_cast<const float4*>(bbase + j * Hn);
            float w0 = invL[0][j];     // wave-uniform broadcast
            float w1 = invL[1][j];
            acc0.x = fmaf(w0, fmaxf(a0.x + b4.x, 0.f), acc0.x);
            acc0.y = fmaf(w0, fmaxf(a0.y + b4.y, 0.f), acc0.y);
            acc0.z = fmaf(w0, fmaxf(a0.z + b4.z, 0.f), acc0.z);
            acc0.w = fmaf(w0, fmaxf(a0.w + b4.w, 0.f), acc0.w);
            acc1.x = fmaf(w1, fmaxf(a1.x + b4.x, 0.f), acc1.x);
            acc1.y = fmaf(w1, fmaxf(a1.y + b4.y, 0.f), acc1.y);
            acc1.z = fmaf(w1, fmaxf(a1.z + b4.z, 0.f), acc1.z);
            acc1.w = fmaf(w1, fmaxf(a1.w + b4.w, 0.f), acc1.w);
        }
        *reinterpret_cast<float4*>(&red[0][c][h4 * 4]) = acc0;
        *reinterpret_cast<float4*>(&red[1][c][h4 * 4]) = acc1;
    }
    __syncthreads();
    if (t < 256) {
        int h = t;
        float v = 0.f;
#pragma unroll
        for (int c = 0; c < 8; ++c) v += red[0][c][h] + red[1][c][h];
        atomicAdd(&rC[b * Hn + h], v);
    }
}

// ---------------------------------------------------------------------------
// Kernel 3: per-batch finish. 4 blocks x 1024 threads (h = t&255, q = t>>8).
// ---------------------------------------------------------------------------
__global__ __launch_bounds__(1024) void finish_kernel(
    const float* __restrict__ rC,
    const float* __restrict__ gg, const float* __restrict__ gb,
    const float* __restrict__ Wf, const float* __restrict__ bfv,
    const float* __restrict__ fg, const float* __restrict__ fb,
    float* __restrict__ rel)
{
    int b = blockIdx.x;
    int t = threadIdx.x;
    int h = t & 255;
    int q = t >> 8;

    __shared__ float rs[256];
    __shared__ float ysum[4][256];
    __shared__ float pS[16], pQ[16];

    if (q == 0)
        rs[h] = gg[h] * (rC[b * Hn + h] + rC[1024 + b]) + 65536.0f * gb[h];
    __syncthreads();

    float y = 0.f;
    const float* Wcol = Wf + (q * 64) * Hn + h;
#pragma unroll 8
    for (int k = 0; k < 64; ++k) y = fmaf(rs[q * 64 + k], Wcol[k * Hn], y);
    ysum[q][h] = y;
    __syncthreads();

    float v = fmaxf(ysum[0][h] + ysum[1][h] + ysum[2][h] + ysum[3][h] + bfv[h], 0.f);

    float sv = v, qv = v * v;
#pragma unroll
    for (int off = 32; off >= 1; off >>= 1) {
        sv += __shfl_xor(sv, off, 64);
        qv += __shfl_xor(qv, off, 64);
    }
    int wid = t >> 6, lane = t & 63;
    if (lane == 0) { pS[wid] = sv; pQ[wid] = qv; }
    __syncthreads();
    float S = 0.f, Q = 0.f;
#pragma unroll
    for (int w = 0; w < 16; ++w) { S += pS[w]; Q += pQ[w]; }
    float m = S * (1.f / 1024.f);
    float var = Q * (1.f / 1024.f) - m * m;
    float inv = rsqrtf(var + LN_EPS);

    if (q == 0)
        rel[b * Hn + h] = (v - m) * inv * fg[h] + fb[h];
}

// ---------------------------------------------------------------------------
// Kernel 4: out[b,n,d] = rel[b,d] + x[b,n,d], float4-vectorized.
// ---------------------------------------------------------------------------
__global__ __launch_bounds__(256) void add_kernel(
    const float* __restrict__ rel, const float* __restrict__ x,
    float* __restrict__ out)
{
    int idx = blockIdx.x * blockDim.x + threadIdx.x;   // float4 units
    int b = idx >> 14;
    int d4 = idx & 63;
    float4 r4 = reinterpret_cast<const float4*>(rel)[b * 64 + d4];
    float4 x4 = reinterpret_cast<const float4*>(x)[idx];
    float4 o;
    o.x = r4.x + x4.x;
    o.y = r4.y + x4.y;
    o.z = r4.z + x4.z;
    o.w = r4.w + x4.w;
    reinterpret_cast<float4*>(out)[idx] = o;
}

// ---------------------------------------------------------------------------
extern "C" void kernel_launch(void* const* d_in, const int* in_sizes, int n_in,
                              void* d_out, int out_size, void* d_ws, size_t ws_size,
                              hipStream_t stream)
{
    const float* x   = (const float*)d_in[0];
    const float* Wg  = (const float*)d_in[1];
    const float* bg  = (const float*)d_in[2];
    const float* gg  = (const float*)d_in[3];
    const float* gb  = (const float*)d_in[4];
    const float* Wf  = (const float*)d_in[5];
    const float* bfv = (const float*)d_in[6];
    const float* fg  = (const float*)d_in[7];
    const float* fb  = (const float*)d_in[8];
    float* out = (float*)d_out;

    float* ws  = (float*)d_ws;
    float* aA  = ws;                 // 1024*256
    float* bB  = ws + 262144;        // 1024*256
    float* rC  = ws + 524288;        // 1024 + 4 atomic accumulators
    float* rel = ws + 525568;        // 4*256

    gemm_ab_kernel<<<dim3(256, 2), 512, 0, stream>>>(x, Wg, bg, aA, bB, rC);
    pair_kernel<<<512, 512, 0, stream>>>(aA, bB, rC);
    finish_kernel<<<4, 1024, 0, stream>>>(rC, gg, gb, Wf, bfv, fg, fb, rel);
    add_kernel<<<256, 256, 0, stream>>>(rel, x, out);
}

// Round 4
// 103.497 us; speedup vs baseline: 1.4549x; 1.4549x over previous
//
#include <hip/hip_runtime.h>

#define LN_EPS 1e-5f

constexpr int Bn = 4, Nn = 256, Dn = 256, Hn = 256;

// ws layout (floats):
//   aA    @ 0        (1024*256)
//   bB    @ 262144   (1024*256)
//   rC    @ 524288   (1024)      -- atomic accumulators r[b,h], zeroed in gemm
//   Cpart @ 525312   (512)       -- per-pair-block C partials (no contention)
//   rel   @ 525824   (1024)

// ---------------------------------------------------------------------------
// Kernel 1: aA[m,h] = x[m,:]@Wg[:D,h] + bg[h]  (half=0)
//           bB[m,h] = x[m,:]@Wg[D:,h]          (half=1)
// Block: 4-row m-tile, 512 threads = (h4 in [0,64), dc in [0,8)).
// float4 W loads (1KB/wave coalesced). Block (0,0) zeroes rC.
// ---------------------------------------------------------------------------
__global__ __launch_bounds__(512) void gemm_ab_kernel(
    const float* __restrict__ x, const float* __restrict__ Wg,
    const float* __restrict__ bg, float* __restrict__ aA,
    float* __restrict__ bB, float* __restrict__ rC)
{
    int mt = blockIdx.x;     // 0..255
    int half = blockIdx.y;   // 0 -> a, 1 -> b
    int m0 = mt * 4;
    int t = threadIdx.x;

    if (mt == 0 && half == 0) {
        for (int k = t; k < 1024; k += 512) rC[k] = 0.0f;
    }

    __shared__ float xs[4][256];
    __shared__ float accP[8][4][256];

    if (t < 256)
        reinterpret_cast<float4*>(&xs[0][0])[t] =
            reinterpret_cast<const float4*>(x + m0 * Dn)[t];
    __syncthreads();

    int h4 = t & 63;
    int dc = t >> 6;         // wave-uniform
    const float* Wp = Wg + (half ? Dn * Hn : 0) + h4 * 4;

    float4 acc[4];
#pragma unroll
    for (int m = 0; m < 4; ++m) acc[m] = make_float4(0.f, 0.f, 0.f, 0.f);

#pragma unroll 4
    for (int dd = 0; dd < 32; ++dd) {
        int d = dc * 32 + dd;
        float4 w = *reinterpret_cast<const float4*>(Wp + d * Hn);
#pragma unroll
        for (int m = 0; m < 4; ++m) {
            float xv = xs[m][d];
            acc[m].x = fmaf(xv, w.x, acc[m].x);
            acc[m].y = fmaf(xv, w.y, acc[m].y);
            acc[m].z = fmaf(xv, w.z, acc[m].z);
            acc[m].w = fmaf(xv, w.w, acc[m].w);
        }
    }
#pragma unroll
    for (int m = 0; m < 4; ++m)
        *reinterpret_cast<float4*>(&accP[dc][m][h4 * 4]) = acc[m];
    __syncthreads();

    int h = t & 255;
    int mh = t >> 8;
    float binit = half ? 0.0f : bg[h];
    float* outp = half ? bB : aA;
#pragma unroll
    for (int mi = 0; mi < 2; ++mi) {
        int m = mh * 2 + mi;
        float v = binit;
#pragma unroll
        for (int c = 0; c < 8; ++c) v += accP[c][m][h];
        outp[(m0 + m) * Hn + h] = v;
    }
}

// ---------------------------------------------------------------------------
// Kernel 2: fused pair block, SINGLE pass over bB.
// Block = (b, 2 i-rows), 512 threads, grid 512 (2 blocks/CU).
// Per j-tile (32 rows, 32KB):
//   stage: thread (jg=t>>4, p=t&15) loads row jg cols {p+16r}r<4 as float4,
//          computes LN stats from the SAME registers, ds_writes to Bs,
//          prefetches next tile, 16-lane shuffle reduce -> invL[i][jg].
//   phase2: thread (h4=t&63, c=t>>6) accumulates over its 4 j's from LDS
//          (wave-consecutive ds_read_b128), A-rows in registers.
// End: LDS combine (red aliases Bs), 1 atomic/h; Cpart[block] (no contention).
// ---------------------------------------------------------------------------
__global__ __launch_bounds__(512, 4) void pair_kernel(
    const float* __restrict__ aA, const float* __restrict__ bB,
    float* __restrict__ rC, float* __restrict__ Cpart)
{
    const int b  = blockIdx.x >> 7;
    const int i0 = (blockIdx.x & 127) * 2;
    const int t  = threadIdx.x;

    __shared__ float Bs[32][260];
    __shared__ float invL[2][32];
    __shared__ float wred[8];

    const int jg = t >> 4;
    const int p  = t & 15;
    const int h4 = t & 63;
    const int c  = t >> 6;    // wave-uniform

    const float* aArow0 = aA + (b * Nn + i0) * Hn;
    const float* aArow1 = aArow0 + Hn;

    // stats-mapping A fragments: h = 4*(p+16r)+{0..3}
    float4 As0[4], As1[4];
#pragma unroll
    for (int r = 0; r < 4; ++r) {
        As0[r] = *reinterpret_cast<const float4*>(aArow0 + 4 * (p + 16 * r));
        As1[r] = *reinterpret_cast<const float4*>(aArow1 + 4 * (p + 16 * r));
    }
    // phase2-mapping A fragments: h = h4*4+{0..3}
    const float4 a0 = *reinterpret_cast<const float4*>(aArow0 + h4 * 4);
    const float4 a1 = *reinterpret_cast<const float4*>(aArow1 + h4 * 4);

    const float* browbase = bB + b * Nn * Hn;

    float4 acc0 = make_float4(0.f, 0.f, 0.f, 0.f);
    float4 acc1 = make_float4(0.f, 0.f, 0.f, 0.f);
    float Csum = 0.f;

    float4 bv[4], bvn[4];
    {
        const float* rp = browbase + jg * Hn;
#pragma unroll
        for (int r = 0; r < 4; ++r)
            bv[r] = *reinterpret_cast<const float4*>(rp + 4 * (p + 16 * r));
    }

    for (int jt = 0; jt < 8; ++jt) {
        // ---- stats from staging registers ----
        float s0 = 0.f, q0 = 0.f, s1 = 0.f, q1 = 0.f;
#pragma unroll
        for (int r = 0; r < 4; ++r) {
            float v;
            v = fmaxf(As0[r].x + bv[r].x, 0.f); s0 += v; q0 = fmaf(v, v, q0);
            v = fmaxf(As0[r].y + bv[r].y, 0.f); s0 += v; q0 = fmaf(v, v, q0);
            v = fmaxf(As0[r].z + bv[r].z, 0.f); s0 += v; q0 = fmaf(v, v, q0);
            v = fmaxf(As0[r].w + bv[r].w, 0.f); s0 += v; q0 = fmaf(v, v, q0);
            v = fmaxf(As1[r].x + bv[r].x, 0.f); s1 += v; q1 = fmaf(v, v, q1);
            v = fmaxf(As1[r].y + bv[r].y, 0.f); s1 += v; q1 = fmaf(v, v, q1);
            v = fmaxf(As1[r].z + bv[r].z, 0.f); s1 += v; q1 = fmaf(v, v, q1);
            v = fmaxf(As1[r].w + bv[r].w, 0.f); s1 += v; q1 = fmaf(v, v, q1);
        }
        // ---- stage to LDS ----
#pragma unroll
        for (int r = 0; r < 4; ++r)
            *reinterpret_cast<float4*>(&Bs[jg][4 * (p + 16 * r)]) = bv[r];
        // ---- prefetch next tile ----
        if (jt < 7) {
            const float* rp = browbase + ((jt + 1) * 32 + jg) * Hn;
#pragma unroll
            for (int r = 0; r < 4; ++r)
                bvn[r] = *reinterpret_cast<const float4*>(rp + 4 * (p + 16 * r));
        }
        // ---- 16-lane reduce -> inv ----
#pragma unroll
        for (int off = 8; off >= 1; off >>= 1) {
            s0 += __shfl_xor(s0, off, 16);
            q0 += __shfl_xor(q0, off, 16);
            s1 += __shfl_xor(s1, off, 16);
            q1 += __shfl_xor(q1, off, 16);
        }
        if (p == 0) {
            float m0 = s0 * (1.f / 256.f), m1 = s1 * (1.f / 256.f);
            float inv0 = rsqrtf(q0 * (1.f / 256.f) - m0 * m0 + LN_EPS);
            float inv1 = rsqrtf(q1 * (1.f / 256.f) - m1 * m1 + LN_EPS);
            invL[0][jg] = inv0;
            invL[1][jg] = inv1;
            Csum -= m0 * inv0 + m1 * inv1;
        }
        __syncthreads();
        // ---- phase 2: weighted accumulate from LDS ----
#pragma unroll
        for (int jj = 0; jj < 4; ++jj) {
            int j = c * 4 + jj;
            float w0 = invL[0][j];
            float w1 = invL[1][j];
            float4 b4 = *reinterpret_cast<const float4*>(&Bs[j][h4 * 4]);
            acc0.x = fmaf(w0, fmaxf(a0.x + b4.x, 0.f), acc0.x);
            acc0.y = fmaf(w0, fmaxf(a0.y + b4.y, 0.f), acc0.y);
            acc0.z = fmaf(w0, fmaxf(a0.z + b4.z, 0.f), acc0.z);
            acc0.w = fmaf(w0, fmaxf(a0.w + b4.w, 0.f), acc0.w);
            acc1.x = fmaf(w1, fmaxf(a1.x + b4.x, 0.f), acc1.x);
            acc1.y = fmaf(w1, fmaxf(a1.y + b4.y, 0.f), acc1.y);
            acc1.z = fmaf(w1, fmaxf(a1.z + b4.z, 0.f), acc1.z);
            acc1.w = fmaf(w1, fmaxf(a1.w + b4.w, 0.f), acc1.w);
        }
        __syncthreads();
#pragma unroll
        for (int r = 0; r < 4; ++r) bv[r] = bvn[r];
    }

    // ---- combine: red aliases Bs (all phase-2 reads done) ----
    float* red = &Bs[0][0];   // red[(i*8+c)*256 + h], 4096 floats
    *reinterpret_cast<float4*>(red + c * 256 + h4 * 4) = acc0;
    *reinterpret_cast<float4*>(red + (8 + c) * 256 + h4 * 4) = acc1;

    float cs = Csum;
#pragma unroll
    for (int off = 32; off >= 1; off >>= 1) cs += __shfl_xor(cs, off, 64);
    if ((t & 63) == 0) wred[t >> 6] = cs;
    __syncthreads();

    if (t < 256) {
        float v = 0.f;
#pragma unroll
        for (int cc = 0; cc < 8; ++cc)
            v += red[cc * 256 + t] + red[(8 + cc) * 256 + t];
        atomicAdd(&rC[b * Hn + t], v);
    }
    if (t == 0) {
        float cb = 0.f;
#pragma unroll
        for (int w = 0; w < 8; ++w) cb += wred[w];
        Cpart[blockIdx.x] = cb;
    }
}

// ---------------------------------------------------------------------------
// Kernel 3: per-batch finish. 4 blocks x 512 threads.
//   Cb = sum of 128 Cpart; rs[h] = gg[h]*(r[b,h]+Cb) + N^2*gb[h]
//   y = relu(rs@Wf + bf); rel = LN(y) (divisor 256)
// ---------------------------------------------------------------------------
__global__ __launch_bounds__(512) void finish_kernel(
    const float* __restrict__ rC, const float* __restrict__ Cpart,
    const float* __restrict__ gg, const float* __restrict__ gb,
    const float* __restrict__ Wf, const float* __restrict__ bfv,
    const float* __restrict__ fg, const float* __restrict__ fb,
    float* __restrict__ rel)
{
    const int b = blockIdx.x;
    const int t = threadIdx.x;
    __shared__ float rs[256];
    __shared__ float ysum[8][260];
    __shared__ float cred[2];
    __shared__ float pS[4], pQ[4];

    float cv = (t < 128) ? Cpart[b * 128 + t] : 0.f;
#pragma unroll
    for (int off = 32; off >= 1; off >>= 1) cv += __shfl_xor(cv, off, 64);
    if (t == 0 || t == 64) cred[t >> 6] = cv;
    __syncthreads();

    if (t < 256) {
        float Cb = cred[0] + cred[1];
        rs[t] = gg[t] * (rC[b * Hn + t] + Cb) + 65536.0f * gb[t];
    }
    __syncthreads();

    const int h4 = t & 63;
    const int kc = t >> 6;   // 0..7, 32 k each
    float4 acc = make_float4(0.f, 0.f, 0.f, 0.f);
    const float* Wp = Wf + h4 * 4;
#pragma unroll 8
    for (int kk = 0; kk < 32; ++kk) {
        int k = kc * 32 + kk;
        float4 w = *reinterpret_cast<const float4*>(Wp + k * Hn);
        float rv = rs[k];
        acc.x = fmaf(rv, w.x, acc.x);
        acc.y = fmaf(rv, w.y, acc.y);
        acc.z = fmaf(rv, w.z, acc.z);
        acc.w = fmaf(rv, w.w, acc.w);
    }
    *reinterpret_cast<float4*>(&ysum[kc][h4 * 4]) = acc;
    __syncthreads();

    float v = 0.f;
    if (t < 256) {
        v = bfv[t];
#pragma unroll
        for (int c = 0; c < 8; ++c) v += ysum[c][t];
        v = fmaxf(v, 0.f);
    }
    float sv = (t < 256) ? v : 0.f;
    float qv = (t < 256) ? v * v : 0.f;
#pragma unroll
    for (int off = 32; off >= 1; off >>= 1) {
        sv += __shfl_xor(sv, off, 64);
        qv += __shfl_xor(qv, off, 64);
    }
    if (t < 256 && (t & 63) == 0) { pS[t >> 6] = sv; pQ[t >> 6] = qv; }
    __syncthreads();

    if (t < 256) {
        float S = pS[0] + pS[1] + pS[2] + pS[3];
        float Q = pQ[0] + pQ[1] + pQ[2] + pQ[3];
        float m = S * (1.f / 256.f);
        float inv = rsqrtf(Q * (1.f / 256.f) - m * m + LN_EPS);
        rel[b * Hn + t] = (v - m) * inv * fg[t] + fb[t];
    }
}

// ---------------------------------------------------------------------------
// Kernel 4: out[b,n,d] = rel[b,d] + x[b,n,d], float4-vectorized.
// ---------------------------------------------------------------------------
__global__ __launch_bounds__(256) void add_kernel(
    const float* __restrict__ rel, const float* __restrict__ x,
    float* __restrict__ out)
{
    int idx = blockIdx.x * blockDim.x + threadIdx.x;   // float4 units
    int b = idx >> 14;
    int d4 = idx & 63;
    float4 r4 = reinterpret_cast<const float4*>(rel)[b * 64 + d4];
    float4 x4 = reinterpret_cast<const float4*>(x)[idx];
    float4 o;
    o.x = r4.x + x4.x;
    o.y = r4.y + x4.y;
    o.z = r4.z + x4.z;
    o.w = r4.w + x4.w;
    reinterpret_cast<float4*>(out)[idx] = o;
}

// ---------------------------------------------------------------------------
extern "C" void kernel_launch(void* const* d_in, const int* in_sizes, int n_in,
                              void* d_out, int out_size, void* d_ws, size_t ws_size,
                              hipStream_t stream)
{
    const float* x   = (const float*)d_in[0];
    const float* Wg  = (const float*)d_in[1];
    const float* bg  = (const float*)d_in[2];
    const float* gg  = (const float*)d_in[3];
    const float* gb  = (const float*)d_in[4];
    const float* Wf  = (const float*)d_in[5];
    const float* bfv = (const float*)d_in[6];
    const float* fg  = (const float*)d_in[7];
    const float* fb  = (const float*)d_in[8];
    float* out = (float*)d_out;

    float* ws    = (float*)d_ws;
    float* aA    = ws;                 // 1024*256
    float* bB    = ws + 262144;        // 1024*256
    float* rC    = ws + 524288;        // 1024
    float* Cpart = ws + 525312;        // 512
    float* rel   = ws + 525824;        // 1024

    gemm_ab_kernel<<<dim3(256, 2), 512, 0, stream>>>(x, Wg, bg, aA, bB, rC);
    pair_kernel<<<512, 512, 0, stream>>>(aA, bB, rC, Cpart);
    finish_kernel<<<4, 512, 0, stream>>>(rC, Cpart, gg, gb, Wf, bfv, fg, fb, rel);
    add_kernel<<<256, 256, 0, stream>>>(rel, x, out);
}